// Round 6
// baseline (118.741 us; speedup 1.0000x reference)
//
#include <hip/hip_runtime.h>
#include <math.h>

#define Ydim 384
#define Xdim 512
#define NPIX (Ydim * Xdim)
#define EPS 1e-4

__device__ __forceinline__ double fast_rcp64(double d) {
    // approx fp32 rcp + 2 fp64 Newton steps -> ~full fp64 accuracy, no IEEE div
    double r = (double)__builtin_amdgcn_rcpf((float)d);
    r = r * (2.0 - d * r);
    r = r * (2.0 - d * r);
    return r;
}

// Fused quad-fit. Block = 256 threads = 8x4 pixel tile (wave w = tile row w,
// subgroup s = pixel x-offset; 8 lanes/pixel, 4 channels/lane).
// __launch_bounds__(256,4): 128-VGPR budget so the 16 gather float4s can stay
// live and issue as one batch. 2D tile shrinks per-block unique-line footprint.
// NOTE: fast path MUST index via the individually-clipped cols[]/rows[] —
// base+r indexing reads OOB when border clamping makes taps degenerate
// (r5 crash: all-clamped taps satisfy the grid-consistency predicate).
__global__ __launch_bounds__(256, 4) void qf_fused_kernel(
    const float* __restrict__ feat0,
    const float* __restrict__ feat1,
    const float* __restrict__ flow,
    float* __restrict__ out)    // (NPIX, 6)
{
    const int b   = blockIdx.x;           // 0..6143
    const int xcd = b & 7;
    const int seq = b >> 3;               // 0..767
    const int tile_x = seq & 63;          // 64 tiles across
    const int tile_y = xcd * 12 + (seq >> 6);   // 96 tile rows, banded per XCD

    const int t   = threadIdx.x;
    const int g   = t >> 3;               // pixel-in-block 0..31
    const int sub = t & 7;                // channel quad
    const int px_x = g & 7, px_y = g >> 3;
    const int x = tile_x * 8 + px_x;
    const int y = tile_y * 4 + px_y;
    const int pix = y * Xdim + x;

    const float u = flow[pix * 3 + 0];
    const float v = flow[pix * 3 + 1];
    const float4 f0 = *(const float4*)(feat0 + (size_t)pix * 32 + sub * 4);

    // Reference op order exactly: p = ((x+u)) + (j-1), per-tap floor/clip.
    const float pxc = (float)x + u;
    const float pyc = (float)y + v;

    int   c0[3], c1[3], r0[3], r1[3];
    float wx[3], wy[3];
#pragma unroll
    for (int j = 0; j < 3; ++j) {
        float px = pxc + (float)(j - 1);
        float fx = floorf(px);
        wx[j] = px - fx;
        int xi = min(max((int)fx, 0), Xdim - 1);
        c0[j] = xi;
        c1[j] = min(xi + 1, Xdim - 1);
        float py = pyc + (float)(j - 1);
        float fy = floorf(py);
        wy[j] = py - fy;
        int yi = min(max((int)fy, 0), Ydim - 1);
        r0[j] = yi;
        r1[j] = min(yi + 1, Ydim - 1);
    }

    float cacc[9];
    const bool fast = (c1[0] == c0[1]) & (c1[1] == c0[2])
                    & (r1[0] == r0[1]) & (r1[1] == r0[2]);

    if (fast) {
        // 4x4 unique corner grid: 16 float4 loads (clipped indices), one batch.
        const int cols[4] = {c0[0], c0[1], c0[2], c1[2]};
        const int rows[4] = {r0[0], r0[1], r0[2], r1[2]};
        float4 F[4][4];
#pragma unroll
        for (int r = 0; r < 4; ++r) {
            const float* rb = feat1 + ((size_t)rows[r] * Xdim) * 32 + sub * 4;
#pragma unroll
            for (int c = 0; c < 4; ++c)
                F[r][c] = *(const float4*)(rb + (size_t)cols[c] * 32);
        }
#pragma unroll
        for (int i = 0; i < 3; ++i) {
            float wyv = wy[i], omwy = 1.f - wyv;
#pragma unroll
            for (int j = 0; j < 3; ++j) {
                float wxv = wx[j], omwx = 1.f - wxv;
                float w00 = omwx * omwy, w01 = wxv * omwy;
                float w10 = omwx * wyv,  w11 = wxv * wyv;
                float4 a = F[i][j], bb = F[i][j + 1], c = F[i + 1][j], d = F[i + 1][j + 1];
                float dx = f0.x - (a.x * w00 + bb.x * w01 + c.x * w10 + d.x * w11);
                float dy = f0.y - (a.y * w00 + bb.y * w01 + c.y * w10 + d.y * w11);
                float dz = f0.z - (a.z * w00 + bb.z * w01 + c.z * w10 + d.z * w11);
                float dw = f0.w - (a.w * w00 + bb.w * w01 + c.w * w10 + d.w * w11);
                cacc[i * 3 + j] = dx * dx + dy * dy + dz * dz + dw * dw;
            }
        }
    } else {
        // Border pixels: exact per-tap 36-load path (clip(x0_clipped+1) rule).
#pragma unroll
        for (int i = 0; i < 3; ++i) {
            float wyv = wy[i], omwy = 1.f - wyv;
            int rb0 = r0[i] * (Xdim * 32);
            int rb1 = r1[i] * (Xdim * 32);
#pragma unroll
            for (int j = 0; j < 3; ++j) {
                const float4 f00 = *(const float4*)(feat1 + rb0 + c0[j] * 32 + sub * 4);
                const float4 f01 = *(const float4*)(feat1 + rb0 + c1[j] * 32 + sub * 4);
                const float4 f10 = *(const float4*)(feat1 + rb1 + c0[j] * 32 + sub * 4);
                const float4 f11 = *(const float4*)(feat1 + rb1 + c1[j] * 32 + sub * 4);
                float wxv = wx[j], omwx = 1.f - wxv;
                float w00 = omwx * omwy, w01 = wxv * omwy;
                float w10 = omwx * wyv,  w11 = wxv * wyv;
                float dx = f0.x - (f00.x * w00 + f01.x * w01 + f10.x * w10 + f11.x * w11);
                float dy = f0.y - (f00.y * w00 + f01.y * w01 + f10.y * w10 + f11.y * w11);
                float dz = f0.z - (f00.z * w00 + f01.z * w01 + f10.z * w10 + f11.z * w11);
                float dw = f0.w - (f00.w * w00 + f01.w * w01 + f10.w * w10 + f11.w * w11);
                cacc[i * 3 + j] = dx * dx + dy * dy + dz * dz + dw * dw;
            }
        }
    }

    // Reduce over the 8 lanes of the subgroup.
#pragma unroll
    for (int m = 1; m <= 4; m <<= 1) {
#pragma unroll
        for (int k = 0; k < 9; ++k)
            cacc[k] += __shfl_xor(cacc[k], m);
    }

    // Compact: lane l (<8) of each wave pulls pixel-l costs from lane 8*l.
    const int laneId = t & 63;
    float c[9];
#pragma unroll
    for (int k = 0; k < 9; ++k)
        c[k] = __shfl(cacc[k], (laneId & 7) * 8);

    if (laneId >= 8) return;

    // ---- Solve: lane l solves the pixel of subgroup l (px_x=l, px_y=wave) --
    float cmin = c[0];
#pragma unroll
    for (int k = 1; k < 9; ++k) cmin = fminf(cmin, c[k]);

    float e[9], sumf = 0.f;
#pragma unroll
    for (int k = 0; k < 9; ++k) {
        e[k] = expf(cmin - c[k]);
        sumf += e[k];
    }
    float invs = 1.f / sumf;

    float w[9], q[9];
#pragma unroll
    for (int k = 0; k < 9; ++k) {
        w[k] = e[k] * invs;
        q[k] = w[k] * c[k];
    }

    // Moments (fp32; design matrix entries in {-1,0,1} => adds only).
    float sc0 = w[0] + w[3] + w[6], sc2 = w[2] + w[5] + w[8];
    float sr0 = w[0] + w[1] + w[2], sr2 = w[6] + w[7] + w[8];
    float S10 = sc2 - sc0, S20 = sc2 + sc0;
    float S01 = sr2 - sr0, S02 = sr2 + sr0;
    float S11 = (w[0] + w[8]) - (w[2] + w[6]);
    float S21 = (w[6] + w[8]) - (w[0] + w[2]);
    float S12 = (w[2] + w[8]) - (w[0] + w[6]);
    float S22 = w[0] + w[2] + w[6] + w[8];
    float S00 = sr0 + w[3] + w[4] + w[5] + sr2;

    float qc0 = q[0] + q[3] + q[6], qc2 = q[2] + q[5] + q[8];
    float qr0 = q[0] + q[1] + q[2], qr2 = q[6] + q[7] + q[8];
    float T10 = qc2 - qc0, T20 = qc2 + qc0;
    float T01 = qr2 - qr0, T02 = qr2 + qr0;
    float T11 = (q[0] + q[8]) - (q[2] + q[6]);
    float T00 = qr0 + q[3] + q[4] + q[5] + qr2;

    // fp64 symmetric elimination (SPD + eps), upper triangle only.
    double M[6][6], rhs[6], ip[6];
    M[0][0] = (double)S20 + EPS; M[0][1] = S22; M[0][2] = S11; M[0][3] = S10; M[0][4] = S21; M[0][5] = S20;
    M[1][1] = (double)S02 + EPS; M[1][2] = S11; M[1][3] = S12; M[1][4] = S01; M[1][5] = S02;
    M[2][2] = (double)S22 + EPS; M[2][3] = S21; M[2][4] = S12; M[2][5] = S11;
    M[3][3] = (double)S20 + EPS; M[3][4] = S11; M[3][5] = S10;
    M[4][4] = (double)S02 + EPS; M[4][5] = S01;
    M[5][5] = (double)S00 + EPS;
    rhs[0] = T20; rhs[1] = T02; rhs[2] = T11; rhs[3] = T10; rhs[4] = T01; rhs[5] = T00;

#pragma unroll
    for (int p = 0; p < 6; ++p) {
        ip[p] = fast_rcp64(M[p][p]);
#pragma unroll
        for (int r = p + 1; r < 6; ++r) {
            double f = M[p][r] * ip[p];
#pragma unroll
            for (int cc = r; cc < 6; ++cc)
                M[r][cc] -= f * M[p][cc];
            rhs[r] -= f * rhs[p];
        }
    }
    double sol[6];
#pragma unroll
    for (int p = 5; p >= 0; --p) {
        double s2 = rhs[p];
#pragma unroll
        for (int cc = p + 1; cc < 6; ++cc) s2 -= M[p][cc] * sol[cc];
        sol[p] = s2 * ip[p];
    }

    const int oy = tile_y * 4 + (t >> 6);          // wave = tile row
    const int ox = tile_x * 8 + laneId;            // lane = x offset
    const int opix = oy * Xdim + ox;
#pragma unroll
    for (int i = 0; i < 6; ++i) out[(size_t)opix * 6 + i] = (float)sol[i];
}

extern "C" void kernel_launch(void* const* d_in, const int* in_sizes, int n_in,
                              void* d_out, int out_size, void* d_ws, size_t ws_size,
                              hipStream_t stream) {
    const float* feat0 = (const float*)d_in[0];
    const float* feat1 = (const float*)d_in[1];
    const float* flow  = (const float*)d_in[2];
    float* out = (float*)d_out;

    qf_fused_kernel<<<dim3(NPIX / 32), dim3(256), 0, stream>>>(feat0, feat1, flow, out);
}

// Round 7
// 111.108 us; speedup vs baseline: 1.0687x; 1.0687x over previous
//
#include <hip/hip_runtime.h>
#include <math.h>

#define Ydim 384
#define Xdim 512
#define NPIX (Ydim * Xdim)
#define EPS 1e-4f

__device__ __forceinline__ float fast_rcp32(float d) {
    float r = __builtin_amdgcn_rcpf(d);
    r = r * (2.f - d * r);           // 1 NR step -> ~1 ulp
    return r;
}

// Fused quad-fit. Block = 512 threads = 64 consecutive pixels (8 lanes/pixel,
// 4 channels/lane, float4). Costs -> LDS -> wave 0 solves all 64 pixels with
// full 64-lane utilization: fp32 softmax/moments/6x6 factorization + ONE
// fp64-residual refinement step (kappa<=6e4, kappa*eps32~4e-3 => refined
// forward error ~1e-5 relative). fp32 solve state fits in VGPRs -> no
// scratch spill (r6: fp64 solve state spilled, +3.9MB WRITE_SIZE).
__global__ __launch_bounds__(512, 4) void qf_fused_kernel(
    const float* __restrict__ feat0,
    const float* __restrict__ feat1,
    const float* __restrict__ flow,
    float* __restrict__ out)    // (NPIX, 6)
{
    __shared__ float cost_lds[64 * 9];

    const int t   = threadIdx.x;
    const int g   = t >> 3;               // pixel-in-block 0..63
    const int sub = t & 7;                // channel quad
    const int pix = blockIdx.x * 64 + g;
    const int y = pix >> 9;               // X = 512
    const int x = pix & (Xdim - 1);

    const float u = flow[pix * 3 + 0];
    const float v = flow[pix * 3 + 1];
    const float4 f0 = *(const float4*)(feat0 + (size_t)pix * 32 + sub * 4);

    // Reference op order exactly: p = ((x+u)) + (j-1), per-tap floor/clip.
    const float pxc = (float)x + u;
    const float pyc = (float)y + v;

    int   c0[3], c1[3], r0[3], r1[3];
    float wx[3], wy[3];
#pragma unroll
    for (int j = 0; j < 3; ++j) {
        float px = pxc + (float)(j - 1);
        float fx = floorf(px);
        wx[j] = px - fx;
        int xi = min(max((int)fx, 0), Xdim - 1);
        c0[j] = xi;
        c1[j] = min(xi + 1, Xdim - 1);
        float py = pyc + (float)(j - 1);
        float fy = floorf(py);
        wy[j] = py - fy;
        int yi = min(max((int)fy, 0), Ydim - 1);
        r0[j] = yi;
        r1[j] = min(yi + 1, Ydim - 1);
    }

    float cacc[9];
    const bool fast = (c1[0] == c0[1]) & (c1[1] == c0[2])
                    & (r1[0] == r0[1]) & (r1[1] == r0[2]);

    if (fast) {
        // 4x4 unique corner grid: 16 float4 loads via the individually
        // CLIPPED cols/rows (base+idx indexing is OOB-unsafe at borders).
        const int cols[4] = {c0[0], c0[1], c0[2], c1[2]};
        const int rows[4] = {r0[0], r0[1], r0[2], r1[2]};
        float4 F[4][4];
#pragma unroll
        for (int r = 0; r < 4; ++r) {
            const float* rb = feat1 + ((size_t)rows[r] * Xdim) * 32 + sub * 4;
#pragma unroll
            for (int c = 0; c < 4; ++c)
                F[r][c] = *(const float4*)(rb + (size_t)cols[c] * 32);
        }
#pragma unroll
        for (int i = 0; i < 3; ++i) {
            float wyv = wy[i], omwy = 1.f - wyv;
#pragma unroll
            for (int j = 0; j < 3; ++j) {
                float wxv = wx[j], omwx = 1.f - wxv;
                float w00 = omwx * omwy, w01 = wxv * omwy;
                float w10 = omwx * wyv,  w11 = wxv * wyv;
                float4 a = F[i][j], bb = F[i][j + 1], c = F[i + 1][j], d = F[i + 1][j + 1];
                float dx = f0.x - (a.x * w00 + bb.x * w01 + c.x * w10 + d.x * w11);
                float dy = f0.y - (a.y * w00 + bb.y * w01 + c.y * w10 + d.y * w11);
                float dz = f0.z - (a.z * w00 + bb.z * w01 + c.z * w10 + d.z * w11);
                float dw = f0.w - (a.w * w00 + bb.w * w01 + c.w * w10 + d.w * w11);
                cacc[i * 3 + j] = dx * dx + dy * dy + dz * dz + dw * dw;
            }
        }
    } else {
        // Border pixels: exact per-tap 36-load path.
#pragma unroll
        for (int i = 0; i < 3; ++i) {
            float wyv = wy[i], omwy = 1.f - wyv;
            int rb0 = r0[i] * (Xdim * 32);
            int rb1 = r1[i] * (Xdim * 32);
#pragma unroll
            for (int j = 0; j < 3; ++j) {
                const float4 f00 = *(const float4*)(feat1 + rb0 + c0[j] * 32 + sub * 4);
                const float4 f01 = *(const float4*)(feat1 + rb0 + c1[j] * 32 + sub * 4);
                const float4 f10 = *(const float4*)(feat1 + rb1 + c0[j] * 32 + sub * 4);
                const float4 f11 = *(const float4*)(feat1 + rb1 + c1[j] * 32 + sub * 4);
                float wxv = wx[j], omwx = 1.f - wxv;
                float w00 = omwx * omwy, w01 = wxv * omwy;
                float w10 = omwx * wyv,  w11 = wxv * wyv;
                float dx = f0.x - (f00.x * w00 + f01.x * w01 + f10.x * w10 + f11.x * w11);
                float dy = f0.y - (f00.y * w00 + f01.y * w01 + f10.y * w10 + f11.y * w11);
                float dz = f0.z - (f00.z * w00 + f01.z * w01 + f10.z * w10 + f11.z * w11);
                float dw = f0.w - (f00.w * w00 + f01.w * w01 + f10.w * w10 + f11.w * w11);
                cacc[i * 3 + j] = dx * dx + dy * dy + dz * dz + dw * dw;
            }
        }
    }

    // Reduce over the 8 lanes of the subgroup (xor-swizzle, conflict-free).
#pragma unroll
    for (int m = 1; m <= 4; m <<= 1) {
#pragma unroll
        for (int k = 0; k < 9; ++k)
            cacc[k] += __shfl_xor(cacc[k], m);
    }
    if (sub == 0) {
#pragma unroll
        for (int k = 0; k < 9; ++k)
            cost_lds[g * 9 + k] = cacc[k];   // stride 9: 2-way bank alias, free
    }
    __syncthreads();

    if (t >= 64) return;    // wave 0 solves all 64 pixels, full lane util

    float c[9];
#pragma unroll
    for (int k = 0; k < 9; ++k) c[k] = cost_lds[t * 9 + k];

    float cmin = c[0];
#pragma unroll
    for (int k = 1; k < 9; ++k) cmin = fminf(cmin, c[k]);

    float e[9], sumf = 0.f;
#pragma unroll
    for (int k = 0; k < 9; ++k) {
        e[k] = expf(cmin - c[k]);
        sumf += e[k];
    }
    float invs = fast_rcp32(sumf);
    invs = invs * (2.f - sumf * invs);   // 2nd NR: full fp32 accuracy

    float w[9], q[9];
#pragma unroll
    for (int k = 0; k < 9; ++k) {
        w[k] = e[k] * invs;
        q[k] = w[k] * c[k];
    }

    // Moments (design entries in {-1,0,1} => adds only).
    float sc0 = w[0] + w[3] + w[6], sc2 = w[2] + w[5] + w[8];
    float sr0 = w[0] + w[1] + w[2], sr2 = w[6] + w[7] + w[8];
    float S10 = sc2 - sc0, S20 = sc2 + sc0;
    float S01 = sr2 - sr0, S02 = sr2 + sr0;
    float S11 = (w[0] + w[8]) - (w[2] + w[6]);
    float S21 = (w[6] + w[8]) - (w[0] + w[2]);
    float S12 = (w[2] + w[8]) - (w[0] + w[6]);
    float S22 = w[0] + w[2] + w[6] + w[8];
    float S00 = sr0 + w[3] + w[4] + w[5] + sr2;

    float qc0 = q[0] + q[3] + q[6], qc2 = q[2] + q[5] + q[8];
    float qr0 = q[0] + q[1] + q[2], qr2 = q[6] + q[7] + q[8];
    float T10 = qc2 - qc0, T20 = qc2 + qc0;
    float T01 = qr2 - qr0, T02 = qr2 + qr0;
    float T11 = (q[0] + q[8]) - (q[2] + q[6]);
    float T00 = qr0 + q[3] + q[4] + q[5] + qr2;

    // M (symmetric, fp32). Basis [x^2,y^2,xy,x,y,1].
    float M[6][6];
    M[0][0] = S20 + EPS; M[0][1] = S22; M[0][2] = S11; M[0][3] = S10; M[0][4] = S21; M[0][5] = S20;
    M[1][0] = S22; M[1][1] = S02 + EPS; M[1][2] = S11; M[1][3] = S12; M[1][4] = S01; M[1][5] = S02;
    M[2][0] = S11; M[2][1] = S11; M[2][2] = S22 + EPS; M[2][3] = S21; M[2][4] = S12; M[2][5] = S11;
    M[3][0] = S10; M[3][1] = S12; M[3][2] = S21; M[3][3] = S20 + EPS; M[3][4] = S11; M[3][5] = S10;
    M[4][0] = S21; M[4][1] = S01; M[4][2] = S12; M[4][3] = S11; M[4][4] = S02 + EPS; M[4][5] = S01;
    M[5][0] = S20; M[5][1] = S02; M[5][2] = S11; M[5][3] = S10; M[5][4] = S01; M[5][5] = S00 + EPS;
    float rhs[6] = {T20, T02, T11, T10, T01, T00};

    // In-place LU (no pivoting; SPD+eps). Multipliers in strict lower part.
    float ip[6];
#pragma unroll
    for (int p = 0; p < 6; ++p) {
        ip[p] = fast_rcp32(M[p][p]);
#pragma unroll
        for (int r = p + 1; r < 6; ++r) {
            float f = M[r][p] * ip[p];
            M[r][p] = f;
#pragma unroll
            for (int cc = p + 1; cc < 6; ++cc)
                M[r][cc] -= f * M[p][cc];
        }
    }

    // Solve L U s = rhs.
    float s[6];
#pragma unroll
    for (int p = 0; p < 6; ++p) {
        float tt = rhs[p];
#pragma unroll
        for (int j = 0; j < 6; ++j) if (j < p) tt -= M[p][j] * s[j];
        s[p] = tt;
    }
#pragma unroll
    for (int p = 5; p >= 0; --p) {
        float tt = s[p];
#pragma unroll
        for (int j = 0; j < 6; ++j) if (j > p) tt -= M[p][j] * s[j];
        s[p] = tt * ip[p];
    }

    // One fp64 refinement step: r = rhs - M0*s (M0 rebuilt exactly from
    // the fp32 moments), then correct with the fp32 factors.
    double s0 = s[0], s1 = s[1], s2 = s[2], s3 = s[3], s4 = s[4], s5 = s[5];
    double dS20 = S20, dS02 = S02, dS22 = S22, dS11 = S11, dS10 = S10,
           dS01 = S01, dS21 = S21, dS12 = S12, dS00 = S00, dE = (double)EPS;
    double rd[6];
    rd[0] = (double)T20 - ((dS20 + dE) * s0 + dS22 * s1 + dS11 * s2 + dS10 * s3 + dS21 * s4 + dS20 * s5);
    rd[1] = (double)T02 - (dS22 * s0 + (dS02 + dE) * s1 + dS11 * s2 + dS12 * s3 + dS01 * s4 + dS02 * s5);
    rd[2] = (double)T11 - (dS11 * s0 + dS11 * s1 + (dS22 + dE) * s2 + dS21 * s3 + dS12 * s4 + dS11 * s5);
    rd[3] = (double)T10 - (dS10 * s0 + dS12 * s1 + dS21 * s2 + (dS20 + dE) * s3 + dS11 * s4 + dS10 * s5);
    rd[4] = (double)T01 - (dS21 * s0 + dS01 * s1 + dS12 * s2 + dS11 * s3 + (dS02 + dE) * s4 + dS01 * s5);
    rd[5] = (double)T00 - (dS20 * s0 + dS02 * s1 + dS11 * s2 + dS10 * s3 + dS01 * s4 + (dS00 + dE) * s5);

    float d[6];
#pragma unroll
    for (int p = 0; p < 6; ++p) {
        float tt = (float)rd[p];
#pragma unroll
        for (int j = 0; j < 6; ++j) if (j < p) tt -= M[p][j] * d[j];
        d[p] = tt;
    }
#pragma unroll
    for (int p = 5; p >= 0; --p) {
        float tt = d[p];
#pragma unroll
        for (int j = 0; j < 6; ++j) if (j > p) tt -= M[p][j] * d[j];
        d[p] = tt * ip[p];
    }

    const int opix = blockIdx.x * 64 + t;
#pragma unroll
    for (int i = 0; i < 6; ++i)
        out[(size_t)opix * 6 + i] = s[i] + d[i];
}

extern "C" void kernel_launch(void* const* d_in, const int* in_sizes, int n_in,
                              void* d_out, int out_size, void* d_ws, size_t ws_size,
                              hipStream_t stream) {
    const float* feat0 = (const float*)d_in[0];
    const float* feat1 = (const float*)d_in[1];
    const float* flow  = (const float*)d_in[2];
    float* out = (float*)d_out;

    qf_fused_kernel<<<dim3(NPIX / 64), dim3(512), 0, stream>>>(feat0, feat1, flow, out);
}